// Round 6
// baseline (399.656 us; speedup 1.0000x reference)
//
#include <hip/hip_runtime.h>
#include <hip/hip_bf16.h>
#include <cstdint>
#include <cstddef>

// ---------------------------------------------------------------------------
// DebugBertLayer: reference overwrites q,k,v with 0.01 AFTER the projections,
// so ctx == 0.01 and ctx @ Wo.T + bo collapses to a per-channel constant
// c[i] = 0.01 * rowsum(Wo)[i] + bo[i].  Real work:
//   LN1(hidden + c) -> GEMM1(+GELU) -> GEMM2 (split-K=2, fused LN2).
// R6: GEMM2+LN2 fused via split-K last-block election (device-scope atomics
// + fences; counters zeroed by prep which precedes in stream order).
// 4 dispatches total — testing the ~20us/dispatch overhead theory.
// ---------------------------------------------------------------------------

typedef __bf16 bf16;
typedef __attribute__((ext_vector_type(8))) __bf16 bf16x8;
typedef __attribute__((ext_vector_type(4))) __bf16 bf16x4;
typedef __attribute__((ext_vector_type(4))) float floatx4;

#define DM    768      // d_model
#define DF    3072     // d_ff
#define MROWS 8192     // B*S = 4*2048

#define N8          (DF * DM / 8)          // 294912 : 8-elem groups per weight
#define CONV_BLOCKS (2 * N8 / 256)         // 2304 convert blocks
#define CVEC_BLOCKS (DM / 4)               // 192 blocks, wave per row

__device__ __forceinline__ void gl2lds16(const void* gp, void* lp) {
  __builtin_amdgcn_global_load_lds(
      (__attribute__((address_space(1))) void*)(void*)gp,
      (__attribute__((address_space(3))) void*)lp,
      16, 0, 0);
}

// fast GELU (tanh form): x * sigmoid(1.5958*(x + 0.044715*x^3))
__device__ __forceinline__ float gelu_fast(float x) {
  float x2 = x * x;
  float m  = x * __builtin_fmaf(-0.1029641f, x2, -2.3025851f);
  float e  = __builtin_amdgcn_exp2f(m);
  return x * __builtin_amdgcn_rcpf(1.0f + e);
}

// ---------------------------------------------------------------------------
// prep: blocks [0, CONV_BLOCKS) convert Wi/Wf fp32->bf16 (8 elem/thread);
//       blocks [CONV_BLOCKS, +CVEC_BLOCKS) compute cvec, one wave per row.
//       First cvec block also zeroes the split-K election counters.
// ---------------------------------------------------------------------------
__global__ __launch_bounds__(256)
void prep_kernel(const float* __restrict__ Wi, const float* __restrict__ Wf,
                 bf16* __restrict__ Wib, bf16* __restrict__ Wfb,
                 const float* __restrict__ Wo, const float* __restrict__ bo,
                 float* __restrict__ cvec, int* __restrict__ ctr) {
  if (blockIdx.x < CONV_BLOCKS) {
    int i = blockIdx.x * 256 + threadIdx.x;
    const float* src = (i < N8) ? Wi : Wf;
    bf16* dst        = (i < N8) ? Wib : Wfb;
    int k            = (i < N8) ? i : i - N8;
    const float4* p = (const float4*)(src + (size_t)k * 8);
    float4 x = p[0], y = p[1];
    bf16x8 o;
    o[0]=(bf16)x.x; o[1]=(bf16)x.y; o[2]=(bf16)x.z; o[3]=(bf16)x.w;
    o[4]=(bf16)y.x; o[5]=(bf16)y.y; o[6]=(bf16)y.z; o[7]=(bf16)y.w;
    *(bf16x8*)(dst + (size_t)k * 8) = o;
  } else {
    if (blockIdx.x == CONV_BLOCKS && threadIdx.x < 64)
      ctr[threadIdx.x] = 0;   // zero election counters (ws is 0xAA-poisoned)
    int row  = (blockIdx.x - CONV_BLOCKS) * 4 + (threadIdx.x >> 6);
    int lane = threadIdx.x & 63;
    const float4* r = (const float4*)(Wo + (size_t)row * DM);
    float s = 0.f;
    #pragma unroll
    for (int t = 0; t < 3; ++t) {
      float4 v = r[lane + t * 64];
      s += v.x + v.y + v.z + v.w;
    }
    #pragma unroll
    for (int o = 32; o > 0; o >>= 1) s += __shfl_xor(s, o);
    if (lane == 0) cvec[row] = 0.01f * s + bo[row];
  }
}

// ---------------------------------------------------------------------------
// attn_out[row] = LN(hidden[row] + cvec) -> bf16.  4 rows/block (wave each).
// ---------------------------------------------------------------------------
__global__ __launch_bounds__(256)
void ln1_kernel(const float* __restrict__ hid, const float* __restrict__ cvec,
                const float* __restrict__ g, const float* __restrict__ b,
                bf16* __restrict__ out) {
  int row  = blockIdx.x * 4 + (threadIdx.x >> 6);
  int lane = threadIdx.x & 63;
  const float4* hrow = (const float4*)(hid + (size_t)row * DM);
  const float4* cv4  = (const float4*)cvec;
  float x[12];
  float s = 0.f, sq = 0.f;
  #pragma unroll
  for (int t = 0; t < 3; ++t) {
    int c = lane + t * 64;
    float4 v = hrow[c];
    float4 cc = cv4[c];
    float x0 = v.x + cc.x, x1 = v.y + cc.y, x2 = v.z + cc.z, x3 = v.w + cc.w;
    x[t*4+0] = x0; x[t*4+1] = x1; x[t*4+2] = x2; x[t*4+3] = x3;
    s  += x0 + x1 + x2 + x3;
    sq += x0*x0 + x1*x1 + x2*x2 + x3*x3;
  }
  #pragma unroll
  for (int o = 32; o > 0; o >>= 1) { s += __shfl_xor(s, o); sq += __shfl_xor(sq, o); }
  float mu  = s * (1.0f / DM);
  float var = sq * (1.0f / DM) - mu * mu;
  float inv = rsqrtf(var + 1e-12f);
  const float4* g4 = (const float4*)g;
  const float4* b4 = (const float4*)b;
  #pragma unroll
  for (int t = 0; t < 3; ++t) {
    int c = lane + t * 64;
    float4 gg = g4[c], bb = b4[c];
    bf16x4 o4;
    o4[0] = (bf16)((x[t*4+0] - mu) * inv * gg.x + bb.x);
    o4[1] = (bf16)((x[t*4+1] - mu) * inv * gg.y + bb.y);
    o4[2] = (bf16)((x[t*4+2] - mu) * inv * gg.z + bb.z);
    o4[3] = (bf16)((x[t*4+3] - mu) * inv * gg.w + bb.w);
    *(bf16x4*)(out + (size_t)row * DM + c * 4) = o4;
  }
}

// ---------------------------------------------------------------------------
// GEMM1: NT bf16 MFMA, 128x128 tile, BK=64, XOR-swizzled staging,
// coalesced LDS-transposed epilogue with fast GELU.  out bf16.
// ---------------------------------------------------------------------------
#define BM 128
#define BN 128
#define BK 64
#define ES 136   // epilogue LDS row stride in bf16 (272 B, 16B-aligned)

__global__ __launch_bounds__(256)
void gemm1(const bf16* __restrict__ A, const bf16* __restrict__ B,
           const float* __restrict__ bias, bf16* __restrict__ out,
           int M, int N, int K) {
  __shared__ __align__(16) unsigned char smem[BM * ES * 2];  // 34816 B
  bf16* lds_a = (bf16*)smem;
  bf16* lds_b = lds_a + BM * BK;

  const int tid   = threadIdx.x;
  const int wave  = tid >> 6;
  const int lane  = tid & 63;
  const int quad  = lane >> 4;
  const int row16 = lane & 15;
  const int xorv  = row16 & 7;

  const int m0 = blockIdx.y * BM;
  const int n0 = blockIdx.x * BN;
  const int wm = (wave >> 1) * 64;
  const int wn = (wave & 1) * 64;

  floatx4 acc[4][4] = {};
  const bf16* Ablk = A + (size_t)m0 * K;
  const bf16* Bblk = B + (size_t)n0 * K;

  for (int kk = 0; kk < K; kk += BK) {
    #pragma unroll
    for (int i = 0; i < 4; ++i) {
      int ci  = tid + 256 * i;
      int r   = ci >> 3;
      int c_g = (ci & 7) ^ (r & 7);
      gl2lds16(Ablk + (size_t)r * K + kk + c_g * 8, lds_a + ci * 8);
      gl2lds16(Bblk + (size_t)r * K + kk + c_g * 8, lds_b + ci * 8);
    }
    __syncthreads();
    #pragma unroll
    for (int ks = 0; ks < BK; ks += 32) {
      const int cs = ((ks >> 3) + quad) ^ xorv;
      bf16x8 af[4], bfr[4];
      #pragma unroll
      for (int i = 0; i < 4; ++i)
        af[i] = *(const bf16x8*)&lds_a[(wm + i * 16 + row16) * BK + cs * 8];
      #pragma unroll
      for (int j = 0; j < 4; ++j)
        bfr[j] = *(const bf16x8*)&lds_b[(wn + j * 16 + row16) * BK + cs * 8];
      #pragma unroll
      for (int i = 0; i < 4; ++i)
        #pragma unroll
        for (int j = 0; j < 4; ++j)
          acc[i][j] = __builtin_amdgcn_mfma_f32_16x16x32_bf16(af[i], bfr[j], acc[i][j], 0, 0, 0);
    }
    __syncthreads();
  }

  bf16* eb = (bf16*)smem;
  float bia[4];
  #pragma unroll
  for (int j = 0; j < 4; ++j) bia[j] = bias[n0 + wn + j * 16 + row16];

  #pragma unroll
  for (int i = 0; i < 4; ++i)
    #pragma unroll
    for (int j = 0; j < 4; ++j) {
      int col = wn + j * 16 + row16;
      #pragma unroll
      for (int r = 0; r < 4; ++r) {
        int row = wm + i * 16 + quad * 4 + r;
        eb[row * ES + col] = (bf16)gelu_fast(acc[i][j][r] + bia[j]);
      }
    }
  __syncthreads();

  const int rsub = tid >> 4;
  const int csub = (tid & 15) * 8;
  #pragma unroll
  for (int c = 0; c < 8; ++c) {
    int row = c * 16 + rsub;
    bf16x8 v = *(const bf16x8*)&eb[row * ES + csub];
    *(bf16x8*)&out[(size_t)(m0 + row) * N + n0 + csub] = v;
  }
}

// ---------------------------------------------------------------------------
// GEMM2 + fused LN2 (split-K=2, last-block election per 128-row group).
// grid (DM/BN=6, MROWS/BM=64, 2).  Partials bf16 in ws.  12th finisher of a
// row group runs LN over its 128 rows and writes fp32 output.
// ---------------------------------------------------------------------------
__global__ __launch_bounds__(256)
void gemm2_ln(const bf16* __restrict__ A, const bf16* __restrict__ B,
              bf16* __restrict__ partial, const bf16* __restrict__ attn,
              const float* __restrict__ bias,
              const float* __restrict__ g, const float* __restrict__ b,
              float* __restrict__ out, int* __restrict__ ctr) {
  const int M = MROWS, N = DM, K = DF;
  __shared__ __align__(16) unsigned char smem[BM * ES * 2];
  bf16* lds_a = (bf16*)smem;
  bf16* lds_b = lds_a + BM * BK;

  const int tid   = threadIdx.x;
  const int wave  = tid >> 6;
  const int lane  = tid & 63;
  const int quad  = lane >> 4;
  const int row16 = lane & 15;
  const int xorv  = row16 & 7;

  const int m0 = blockIdx.y * BM;
  const int n0 = blockIdx.x * BN;
  const int wm = (wave >> 1) * 64;
  const int wn = (wave & 1) * 64;
  const int kbeg = blockIdx.z * (K / 2);
  const int kend = kbeg + K / 2;

  floatx4 acc[4][4] = {};
  const bf16* Ablk = A + (size_t)m0 * K;
  const bf16* Bblk = B + (size_t)n0 * K;

  for (int kk = kbeg; kk < kend; kk += BK) {
    #pragma unroll
    for (int i = 0; i < 4; ++i) {
      int ci  = tid + 256 * i;
      int r   = ci >> 3;
      int c_g = (ci & 7) ^ (r & 7);
      gl2lds16(Ablk + (size_t)r * K + kk + c_g * 8, lds_a + ci * 8);
      gl2lds16(Bblk + (size_t)r * K + kk + c_g * 8, lds_b + ci * 8);
    }
    __syncthreads();
    #pragma unroll
    for (int ks = 0; ks < BK; ks += 32) {
      const int cs = ((ks >> 3) + quad) ^ xorv;
      bf16x8 af[4], bfr[4];
      #pragma unroll
      for (int i = 0; i < 4; ++i)
        af[i] = *(const bf16x8*)&lds_a[(wm + i * 16 + row16) * BK + cs * 8];
      #pragma unroll
      for (int j = 0; j < 4; ++j)
        bfr[j] = *(const bf16x8*)&lds_b[(wn + j * 16 + row16) * BK + cs * 8];
      #pragma unroll
      for (int i = 0; i < 4; ++i)
        #pragma unroll
        for (int j = 0; j < 4; ++j)
          acc[i][j] = __builtin_amdgcn_mfma_f32_16x16x32_bf16(af[i], bfr[j], acc[i][j], 0, 0, 0);
    }
    __syncthreads();
  }

  // epilogue: partial (bf16) via LDS transpose, coalesced stores
  bf16* eb = (bf16*)smem;
  #pragma unroll
  for (int i = 0; i < 4; ++i)
    #pragma unroll
    for (int j = 0; j < 4; ++j) {
      int col = wn + j * 16 + row16;
      #pragma unroll
      for (int r = 0; r < 4; ++r) {
        int row = wm + i * 16 + quad * 4 + r;
        eb[row * ES + col] = (bf16)acc[i][j][r];
      }
    }
  __syncthreads();

  bf16* outp = partial + (size_t)blockIdx.z * M * N;
  const int rsub = tid >> 4;
  const int csub = (tid & 15) * 8;
  #pragma unroll
  for (int c = 0; c < 8; ++c) {
    int row = c * 16 + rsub;
    bf16x8 v = *(const bf16x8*)&eb[row * ES + csub];
    *(bf16x8*)&outp[(size_t)(m0 + row) * N + n0 + csub] = v;
  }

  // ---- split-K election: 12th finisher of this row group does LN2 ----
  __threadfence();                       // release partial stores (device)
  __shared__ int elect;
  if (tid == 0) elect = atomicAdd(&ctr[blockIdx.y], 1);
  __syncthreads();
  if (elect != 11) return;
  __threadfence();                       // acquire: invalidate stale caches

  const bf16* p0 = partial;
  const bf16* p1 = partial + (size_t)M * N;
  const float4* bi4 = (const float4*)bias;
  const float4* g4  = (const float4*)g;
  const float4* b4  = (const float4*)b;

  for (int rr = wave; rr < BM; rr += 4) {
    int row = m0 + rr;
    const bf16* r0 = p0 + (size_t)row * DM;
    const bf16* r1 = p1 + (size_t)row * DM;
    const bf16* ar = attn + (size_t)row * DM;
    float x[12];
    float s = 0.f, sq = 0.f;
    #pragma unroll
    for (int t = 0; t < 3; ++t) {
      int c = lane + t * 64;
      bf16x4 a  = *(const bf16x4*)(r0 + c * 4);
      bf16x4 d  = *(const bf16x4*)(r1 + c * 4);
      bf16x4 rv = *(const bf16x4*)(ar + c * 4);
      float4 bb = bi4[c];
      float x0 = (float)a[0] + (float)d[0] + bb.x + (float)rv[0];
      float x1 = (float)a[1] + (float)d[1] + bb.y + (float)rv[1];
      float x2 = (float)a[2] + (float)d[2] + bb.z + (float)rv[2];
      float x3 = (float)a[3] + (float)d[3] + bb.w + (float)rv[3];
      x[t*4+0] = x0; x[t*4+1] = x1; x[t*4+2] = x2; x[t*4+3] = x3;
      s  += x0 + x1 + x2 + x3;
      sq += x0*x0 + x1*x1 + x2*x2 + x3*x3;
    }
    #pragma unroll
    for (int o = 32; o > 0; o >>= 1) { s += __shfl_xor(s, o); sq += __shfl_xor(sq, o); }
    float mu  = s * (1.0f / DM);
    float var = sq * (1.0f / DM) - mu * mu;
    float inv = rsqrtf(var + 1e-12f);
    float4* orow = (float4*)(out + (size_t)row * DM);
    #pragma unroll
    for (int t = 0; t < 3; ++t) {
      int c = lane + t * 64;
      float4 gg = g4[c], bb = b4[c];
      float4 o;
      o.x = (x[t*4+0] - mu) * inv * gg.x + bb.x;
      o.y = (x[t*4+1] - mu) * inv * gg.y + bb.y;
      o.z = (x[t*4+2] - mu) * inv * gg.z + bb.z;
      o.w = (x[t*4+3] - mu) * inv * gg.w + bb.w;
      orow[c] = o;
    }
  }
}

// ---------------------------------------------------------------------------
extern "C" void kernel_launch(void* const* d_in, const int* in_sizes, int n_in,
                              void* d_out, int out_size, void* d_ws, size_t ws_size,
                              hipStream_t stream) {
  (void)in_sizes; (void)n_in; (void)out_size; (void)ws_size;

  const float* hidden = (const float*)d_in[0];
  const float* Wo     = (const float*)d_in[7];
  const float* bo     = (const float*)d_in[8];
  const float* ln1_g  = (const float*)d_in[9];
  const float* ln1_b  = (const float*)d_in[10];
  const float* Wi     = (const float*)d_in[11];
  const float* bi     = (const float*)d_in[12];
  const float* Wf     = (const float*)d_in[13];
  const float* bf_    = (const float*)d_in[14];
  const float* ln2_g  = (const float*)d_in[15];
  const float* ln2_b  = (const float*)d_in[16];
  float* out = (float*)d_out;

  // workspace layout (~98 MB)
  char* w = (char*)d_ws;
  float* cvec = (float*)w;                 // 3072 B
  int*   ctr  = (int*)(w + 3072);          // 256 B (64 counters)
  size_t off = 4096;
  bf16* attn = (bf16*)(w + off); off += (size_t)MROWS * DM * 2;        // 12.6 MB
  bf16* h    = (bf16*)(w + off); off += (size_t)MROWS * DF * 2;        // 50.3 MB
  bf16* pre  = (bf16*)(w + off); off += (size_t)2 * MROWS * DM * 2;    // 25.2 MB
  bf16* Wib  = (bf16*)(w + off); off += (size_t)DF * DM * 2;           // 4.7 MB
  bf16* Wfb  = (bf16*)(w + off);                                       // 4.7 MB

  // 0. weight converts + cvec + counter zeroing, one dispatch
  prep_kernel<<<dim3(CONV_BLOCKS + CVEC_BLOCKS), dim3(256), 0, stream>>>(
      Wi, Wf, Wib, Wfb, Wo, bo, cvec, ctr);

  // 1. attn = LN1(hidden + cvec)  (bf16)
  ln1_kernel<<<dim3(MROWS / 4), dim3(256), 0, stream>>>(hidden, cvec, ln1_g, ln1_b, attn);

  // 2. h = gelu(attn @ Wi^T + bi)      M=8192 N=3072 K=768
  gemm1<<<dim3(DF / BN, MROWS / BM), dim3(256), 0, stream>>>(
      attn, Wib, bi, h, MROWS, DF, DM);

  // 3. pre[z] = h @ Wf^T ; elected block: out = LN2(pre0+pre1+bf+attn)
  gemm2_ln<<<dim3(DM / BN, MROWS / BM, 2), dim3(256), 0, stream>>>(
      h, Wfb, pre, attn, bf_, ln2_g, ln2_b, out, ctr);
}

// Round 7
// 229.936 us; speedup vs baseline: 1.7381x; 1.7381x over previous
//
#include <hip/hip_runtime.h>
#include <hip/hip_bf16.h>
#include <cstdint>
#include <cstddef>

// ---------------------------------------------------------------------------
// DebugBertLayer: reference overwrites q,k,v with 0.01 AFTER the projections,
// so ctx == 0.01 and ctx @ Wo.T + bo collapses to a per-channel constant
// c[i] = 0.01 * rowsum(Wo)[i] + bo[i].  Real work:
//   LN1(hidden + c) -> GEMM1(+GELU) -> GEMM2 (split-K=2) -> LN2(combine).
// R7: REVERT of R6's fused split-K election LN (device-scope fences + 64-block
// tail cost ~190us).  Back to R5 structure, plus XCD-aware grid remap:
// grid (ygroup, xz) makes linear block id = y + 64*xz, so all blocks sharing
// an m-row-group have id%8 = y%8 -> same XCD -> h/A row-groups fetched into
// one L2 instead of up to 8 (GEMM2 FETCH was 3x its unique input).
// ---------------------------------------------------------------------------

typedef __bf16 bf16;
typedef __attribute__((ext_vector_type(8))) __bf16 bf16x8;
typedef __attribute__((ext_vector_type(4))) __bf16 bf16x4;
typedef __attribute__((ext_vector_type(4))) float floatx4;

#define DM    768      // d_model
#define DF    3072     // d_ff
#define MROWS 8192     // B*S = 4*2048

#define N8          (DF * DM / 8)          // 294912 : 8-elem groups per weight
#define CONV_BLOCKS (2 * N8 / 256)         // 2304 convert blocks
#define CVEC_BLOCKS (DM / 4)               // 192 blocks, wave per row

__device__ __forceinline__ void gl2lds16(const void* gp, void* lp) {
  __builtin_amdgcn_global_load_lds(
      (__attribute__((address_space(1))) void*)(void*)gp,
      (__attribute__((address_space(3))) void*)lp,
      16, 0, 0);
}

// fast GELU (tanh form): x * sigmoid(1.5958*(x + 0.044715*x^3))
__device__ __forceinline__ float gelu_fast(float x) {
  float x2 = x * x;
  float m  = x * __builtin_fmaf(-0.1029641f, x2, -2.3025851f);
  float e  = __builtin_amdgcn_exp2f(m);
  return x * __builtin_amdgcn_rcpf(1.0f + e);
}

// ---------------------------------------------------------------------------
// prep: blocks [0, CONV_BLOCKS) convert Wi/Wf fp32->bf16 (8 elem/thread);
//       blocks [CONV_BLOCKS, +CVEC_BLOCKS) compute cvec, one wave per row.
// ---------------------------------------------------------------------------
__global__ __launch_bounds__(256)
void prep_kernel(const float* __restrict__ Wi, const float* __restrict__ Wf,
                 bf16* __restrict__ Wib, bf16* __restrict__ Wfb,
                 const float* __restrict__ Wo, const float* __restrict__ bo,
                 float* __restrict__ cvec) {
  if (blockIdx.x < CONV_BLOCKS) {
    int i = blockIdx.x * 256 + threadIdx.x;
    const float* src = (i < N8) ? Wi : Wf;
    bf16* dst        = (i < N8) ? Wib : Wfb;
    int k            = (i < N8) ? i : i - N8;
    const float4* p = (const float4*)(src + (size_t)k * 8);
    float4 x = p[0], y = p[1];
    bf16x8 o;
    o[0]=(bf16)x.x; o[1]=(bf16)x.y; o[2]=(bf16)x.z; o[3]=(bf16)x.w;
    o[4]=(bf16)y.x; o[5]=(bf16)y.y; o[6]=(bf16)y.z; o[7]=(bf16)y.w;
    *(bf16x8*)(dst + (size_t)k * 8) = o;
  } else {
    int row  = (blockIdx.x - CONV_BLOCKS) * 4 + (threadIdx.x >> 6);
    int lane = threadIdx.x & 63;
    const float4* r = (const float4*)(Wo + (size_t)row * DM);
    float s = 0.f;
    #pragma unroll
    for (int t = 0; t < 3; ++t) {
      float4 v = r[lane + t * 64];
      s += v.x + v.y + v.z + v.w;
    }
    #pragma unroll
    for (int o = 32; o > 0; o >>= 1) s += __shfl_xor(s, o);
    if (lane == 0) cvec[row] = 0.01f * s + bo[row];
  }
}

// ---------------------------------------------------------------------------
// attn_out[row] = LN(hidden[row] + cvec) -> bf16.  4 rows/block (wave each).
// ---------------------------------------------------------------------------
__global__ __launch_bounds__(256)
void ln1_kernel(const float* __restrict__ hid, const float* __restrict__ cvec,
                const float* __restrict__ g, const float* __restrict__ b,
                bf16* __restrict__ out) {
  int row  = blockIdx.x * 4 + (threadIdx.x >> 6);
  int lane = threadIdx.x & 63;
  const float4* hrow = (const float4*)(hid + (size_t)row * DM);
  const float4* cv4  = (const float4*)cvec;
  float x[12];
  float s = 0.f, sq = 0.f;
  #pragma unroll
  for (int t = 0; t < 3; ++t) {
    int c = lane + t * 64;
    float4 v = hrow[c];
    float4 cc = cv4[c];
    float x0 = v.x + cc.x, x1 = v.y + cc.y, x2 = v.z + cc.z, x3 = v.w + cc.w;
    x[t*4+0] = x0; x[t*4+1] = x1; x[t*4+2] = x2; x[t*4+3] = x3;
    s  += x0 + x1 + x2 + x3;
    sq += x0*x0 + x1*x1 + x2*x2 + x3*x3;
  }
  #pragma unroll
  for (int o = 32; o > 0; o >>= 1) { s += __shfl_xor(s, o); sq += __shfl_xor(sq, o); }
  float mu  = s * (1.0f / DM);
  float var = sq * (1.0f / DM) - mu * mu;
  float inv = rsqrtf(var + 1e-12f);
  const float4* g4 = (const float4*)g;
  const float4* b4 = (const float4*)b;
  #pragma unroll
  for (int t = 0; t < 3; ++t) {
    int c = lane + t * 64;
    float4 gg = g4[c], bb = b4[c];
    bf16x4 o4;
    o4[0] = (bf16)((x[t*4+0] - mu) * inv * gg.x + bb.x);
    o4[1] = (bf16)((x[t*4+1] - mu) * inv * gg.y + bb.y);
    o4[2] = (bf16)((x[t*4+2] - mu) * inv * gg.z + bb.z);
    o4[3] = (bf16)((x[t*4+3] - mu) * inv * gg.w + bb.w);
    *(bf16x4*)(out + (size_t)row * DM + c * 4) = o4;
  }
}

// ---------------------------------------------------------------------------
// out[row] = LN( p0 + p1 + bias + attn )   (bf16 partials) -> fp32 out
// ---------------------------------------------------------------------------
__global__ __launch_bounds__(256)
void ln2_kernel(const bf16* __restrict__ p0, const bf16* __restrict__ p1,
                const float* __restrict__ bias, const bf16* __restrict__ attn,
                const float* __restrict__ g, const float* __restrict__ b,
                float* __restrict__ out) {
  int row  = blockIdx.x * 4 + (threadIdx.x >> 6);
  int lane = threadIdx.x & 63;
  const bf16* r0 = p0 + (size_t)row * DM;
  const bf16* r1 = p1 + (size_t)row * DM;
  const bf16* ar = attn + (size_t)row * DM;
  const float4* bi4 = (const float4*)bias;
  float x[12];
  float s = 0.f, sq = 0.f;
  #pragma unroll
  for (int t = 0; t < 3; ++t) {
    int c = lane + t * 64;
    bf16x4 a = *(const bf16x4*)(r0 + c * 4);
    bf16x4 d = *(const bf16x4*)(r1 + c * 4);
    bf16x4 rv = *(const bf16x4*)(ar + c * 4);
    float4 bb = bi4[c];
    float x0 = (float)a[0] + (float)d[0] + bb.x + (float)rv[0];
    float x1 = (float)a[1] + (float)d[1] + bb.y + (float)rv[1];
    float x2 = (float)a[2] + (float)d[2] + bb.z + (float)rv[2];
    float x3 = (float)a[3] + (float)d[3] + bb.w + (float)rv[3];
    x[t*4+0] = x0; x[t*4+1] = x1; x[t*4+2] = x2; x[t*4+3] = x3;
    s  += x0 + x1 + x2 + x3;
    sq += x0*x0 + x1*x1 + x2*x2 + x3*x3;
  }
  #pragma unroll
  for (int o = 32; o > 0; o >>= 1) { s += __shfl_xor(s, o); sq += __shfl_xor(sq, o); }
  float mu  = s * (1.0f / DM);
  float var = sq * (1.0f / DM) - mu * mu;
  float inv = rsqrtf(var + 1e-12f);
  const float4* g4 = (const float4*)g;
  const float4* b4 = (const float4*)b;
  float4* orow = (float4*)(out + (size_t)row * DM);
  #pragma unroll
  for (int t = 0; t < 3; ++t) {
    int c = lane + t * 64;
    float4 gg = g4[c], bb = b4[c];
    float4 o;
    o.x = (x[t*4+0] - mu) * inv * gg.x + bb.x;
    o.y = (x[t*4+1] - mu) * inv * gg.y + bb.y;
    o.z = (x[t*4+2] - mu) * inv * gg.z + bb.z;
    o.w = (x[t*4+3] - mu) * inv * gg.w + bb.w;
    orow[c] = o;
  }
}

// ---------------------------------------------------------------------------
// NT bf16 MFMA GEMM, 128x128 tile, BK=64, 4 waves of 4x4 16x16x32 tiles.
// XOR-swizzled LDS staging (conflict-free).  Coalesced LDS-transposed
// epilogue.  EPI==0: gelu_fast(acc+bias) bf16;  EPI==1: bf16 split-K partial.
// Grid is (ygroups, xz): linear id = y + gridX*xz  ->  id%8 == y%8 for all
// blocks of an m-row-group  ->  same XCD, A/h rows fetched into one L2.
// NB = n-blocks per xz dimension (x = xz % NB, z = xz / NB).
// ---------------------------------------------------------------------------
#define BM 128
#define BN 128
#define BK 64
#define ES 136   // epilogue LDS row stride in bf16 (272 B, 16B-aligned)

template <int EPI>
__global__ __launch_bounds__(256)
void gemm_nt(const bf16* __restrict__ A, const bf16* __restrict__ B,
             const float* __restrict__ bias,
             bf16* __restrict__ out, int M, int N, int K, int ksplit, int NB) {
  __shared__ __align__(16) unsigned char smem[BM * ES * 2];  // 34816 B
  bf16* lds_a = (bf16*)smem;
  bf16* lds_b = lds_a + BM * BK;

  const int tid   = threadIdx.x;
  const int wave  = tid >> 6;
  const int lane  = tid & 63;
  const int quad  = lane >> 4;
  const int row16 = lane & 15;
  const int xorv  = row16 & 7;

  const int ygrp = blockIdx.x;          // m-row-group (fast index -> XCD key)
  const int xz   = blockIdx.y;
  const int xb   = xz % NB;             // n-block
  const int zb   = xz / NB;             // k-split

  const int m0 = ygrp * BM;
  const int n0 = xb * BN;
  const int wm = (wave >> 1) * 64;
  const int wn = (wave & 1) * 64;

  const int kbeg = zb * ksplit;
  const int kend = kbeg + ksplit;

  floatx4 acc[4][4] = {};
  const bf16* Ablk = A + (size_t)m0 * K;
  const bf16* Bblk = B + (size_t)n0 * K;

  for (int kk = kbeg; kk < kend; kk += BK) {
    #pragma unroll
    for (int i = 0; i < 4; ++i) {
      int ci  = tid + 256 * i;
      int r   = ci >> 3;
      int c_g = (ci & 7) ^ (r & 7);     // swizzled source chunk
      gl2lds16(Ablk + (size_t)r * K + kk + c_g * 8, lds_a + ci * 8);
      gl2lds16(Bblk + (size_t)r * K + kk + c_g * 8, lds_b + ci * 8);
    }
    __syncthreads();

    #pragma unroll
    for (int ks = 0; ks < BK; ks += 32) {
      const int cs = ((ks >> 3) + quad) ^ xorv;
      bf16x8 af[4], bfr[4];
      #pragma unroll
      for (int i = 0; i < 4; ++i)
        af[i] = *(const bf16x8*)&lds_a[(wm + i * 16 + row16) * BK + cs * 8];
      #pragma unroll
      for (int j = 0; j < 4; ++j)
        bfr[j] = *(const bf16x8*)&lds_b[(wn + j * 16 + row16) * BK + cs * 8];
      #pragma unroll
      for (int i = 0; i < 4; ++i)
        #pragma unroll
        for (int j = 0; j < 4; ++j)
          acc[i][j] = __builtin_amdgcn_mfma_f32_16x16x32_bf16(af[i], bfr[j], acc[i][j], 0, 0, 0);
    }
    __syncthreads();
  }

  // ---- epilogue: transpose through LDS, then coalesced stores ----
  bf16* eb = (bf16*)smem;

  float bia[4];
  if constexpr (EPI == 0) {
    #pragma unroll
    for (int j = 0; j < 4; ++j) bia[j] = bias[n0 + wn + j * 16 + row16];
  }

  #pragma unroll
  for (int i = 0; i < 4; ++i) {
    #pragma unroll
    for (int j = 0; j < 4; ++j) {
      int col = wn + j * 16 + row16;
      #pragma unroll
      for (int r = 0; r < 4; ++r) {
        int row = wm + i * 16 + quad * 4 + r;
        float x = acc[i][j][r];
        if constexpr (EPI == 0) x = gelu_fast(x + bia[j]);
        eb[row * ES + col] = (bf16)x;
      }
    }
  }
  __syncthreads();

  bf16* outp = out + (EPI == 1 ? (size_t)zb * M * N : 0);
  const int rsub = tid >> 4;
  const int csub = (tid & 15) * 8;
  #pragma unroll
  for (int c = 0; c < 8; ++c) {
    int row = c * 16 + rsub;
    bf16x8 v = *(const bf16x8*)&eb[row * ES + csub];
    *(bf16x8*)&outp[(size_t)(m0 + row) * N + n0 + csub] = v;
  }
}

// ---------------------------------------------------------------------------
extern "C" void kernel_launch(void* const* d_in, const int* in_sizes, int n_in,
                              void* d_out, int out_size, void* d_ws, size_t ws_size,
                              hipStream_t stream) {
  (void)in_sizes; (void)n_in; (void)out_size; (void)ws_size;

  const float* hidden = (const float*)d_in[0];
  const float* Wo     = (const float*)d_in[7];
  const float* bo     = (const float*)d_in[8];
  const float* ln1_g  = (const float*)d_in[9];
  const float* ln1_b  = (const float*)d_in[10];
  const float* Wi     = (const float*)d_in[11];
  const float* bi     = (const float*)d_in[12];
  const float* Wf     = (const float*)d_in[13];
  const float* bf_    = (const float*)d_in[14];
  const float* ln2_g  = (const float*)d_in[15];
  const float* ln2_b  = (const float*)d_in[16];
  float* out = (float*)d_out;

  // workspace layout (~98 MB)
  char* w = (char*)d_ws;
  float* cvec = (float*)w;
  size_t off = 4096;
  bf16* attn = (bf16*)(w + off); off += (size_t)MROWS * DM * 2;        // 12.6 MB
  bf16* h    = (bf16*)(w + off); off += (size_t)MROWS * DF * 2;        // 50.3 MB
  bf16* pre  = (bf16*)(w + off); off += (size_t)2 * MROWS * DM * 2;    // 25.2 MB
  bf16* Wib  = (bf16*)(w + off); off += (size_t)DF * DM * 2;           // 4.7 MB
  bf16* Wfb  = (bf16*)(w + off);                                       // 4.7 MB

  // 0. weight converts + cvec, one dispatch
  prep_kernel<<<dim3(CONV_BLOCKS + CVEC_BLOCKS), dim3(256), 0, stream>>>(
      Wi, Wf, Wib, Wfb, Wo, bo, cvec);

  // 1. attn = LN1(hidden + cvec)  (bf16)
  ln1_kernel<<<dim3(MROWS / 4), dim3(256), 0, stream>>>(hidden, cvec, ln1_g, ln1_b, attn);

  // 2. h = gelu(attn @ Wi^T + bi)      M=8192 N=3072 K=768
  //    grid (64 ygroups, 24 n-blocks): same-m blocks share an XCD
  gemm_nt<0><<<dim3(MROWS / BM, DF / BN), dim3(256), 0, stream>>>(
      attn, Wib, bi, h, MROWS, DF, DM, DM, DF / BN);

  // 3. pre[z] = h @ Wf^T (K-half z)    M=8192 N=768 K=3072, split-K=2
  //    grid (64 ygroups, 6 n-blocks x 2 z): same-m blocks share an XCD
  gemm_nt<1><<<dim3(MROWS / BM, (DM / BN) * 2), dim3(256), 0, stream>>>(
      h, Wfb, nullptr, pre, MROWS, DM, DF, DF / 2, DM / BN);

  // 4. out = LN2(pre0 + pre1 + bf + attn)
  ln2_kernel<<<dim3(MROWS / 4), dim3(256), 0, stream>>>(
      pre, pre + (size_t)MROWS * DM, bf_, attn, ln2_g, ln2_b, out);
}

// Round 8
// 225.236 us; speedup vs baseline: 1.7744x; 1.0209x over previous
//
#include <hip/hip_runtime.h>
#include <hip/hip_bf16.h>
#include <cstdint>
#include <cstddef>

// ---------------------------------------------------------------------------
// DebugBertLayer: reference overwrites q,k,v with 0.01 AFTER the projections,
// so ctx == 0.01 and ctx @ Wo.T + bo collapses to a per-channel constant
// c[i] = 0.01 * rowsum(Wo)[i] + bo[i].  Real work:
//   LN1(hidden + c) -> GEMM1(+GELU) -> GEMM2 (split-K=2) -> LN2(combine).
// R8: K-loop switched from 4x4 x mfma_16x16x32 to 2x2 x mfma_32x32x16 per
// wave (same 64x64 wave tile, same FLOPs): halves MFMA instruction count and
// cuts matrix-pipe cycles ~17% (m119), attacking the VALU/MFMA issue
// contention (VALUBusy 53% > MfmaUtil 28%).  Everything else = R7 (XCD-aware
// grid remap, XOR-swizzled staging, coalesced LDS-transposed epilogue).
// ---------------------------------------------------------------------------

typedef __bf16 bf16;
typedef __attribute__((ext_vector_type(8))) __bf16 bf16x8;
typedef __attribute__((ext_vector_type(4))) __bf16 bf16x4;
typedef __attribute__((ext_vector_type(16))) float floatx16;

#define DM    768      // d_model
#define DF    3072     // d_ff
#define MROWS 8192     // B*S = 4*2048

#define N8          (DF * DM / 8)          // 294912 : 8-elem groups per weight
#define CONV_BLOCKS (2 * N8 / 256)         // 2304 convert blocks
#define CVEC_BLOCKS (DM / 4)               // 192 blocks, wave per row

__device__ __forceinline__ void gl2lds16(const void* gp, void* lp) {
  __builtin_amdgcn_global_load_lds(
      (__attribute__((address_space(1))) void*)(void*)gp,
      (__attribute__((address_space(3))) void*)lp,
      16, 0, 0);
}

// fast GELU (tanh form): x * sigmoid(1.5958*(x + 0.044715*x^3))
__device__ __forceinline__ float gelu_fast(float x) {
  float x2 = x * x;
  float m  = x * __builtin_fmaf(-0.1029641f, x2, -2.3025851f);
  float e  = __builtin_amdgcn_exp2f(m);
  return x * __builtin_amdgcn_rcpf(1.0f + e);
}

// ---------------------------------------------------------------------------
// prep: blocks [0, CONV_BLOCKS) convert Wi/Wf fp32->bf16 (8 elem/thread);
//       blocks [CONV_BLOCKS, +CVEC_BLOCKS) compute cvec, one wave per row.
// ---------------------------------------------------------------------------
__global__ __launch_bounds__(256)
void prep_kernel(const float* __restrict__ Wi, const float* __restrict__ Wf,
                 bf16* __restrict__ Wib, bf16* __restrict__ Wfb,
                 const float* __restrict__ Wo, const float* __restrict__ bo,
                 float* __restrict__ cvec) {
  if (blockIdx.x < CONV_BLOCKS) {
    int i = blockIdx.x * 256 + threadIdx.x;
    const float* src = (i < N8) ? Wi : Wf;
    bf16* dst        = (i < N8) ? Wib : Wfb;
    int k            = (i < N8) ? i : i - N8;
    const float4* p = (const float4*)(src + (size_t)k * 8);
    float4 x = p[0], y = p[1];
    bf16x8 o;
    o[0]=(bf16)x.x; o[1]=(bf16)x.y; o[2]=(bf16)x.z; o[3]=(bf16)x.w;
    o[4]=(bf16)y.x; o[5]=(bf16)y.y; o[6]=(bf16)y.z; o[7]=(bf16)y.w;
    *(bf16x8*)(dst + (size_t)k * 8) = o;
  } else {
    int row  = (blockIdx.x - CONV_BLOCKS) * 4 + (threadIdx.x >> 6);
    int lane = threadIdx.x & 63;
    const float4* r = (const float4*)(Wo + (size_t)row * DM);
    float s = 0.f;
    #pragma unroll
    for (int t = 0; t < 3; ++t) {
      float4 v = r[lane + t * 64];
      s += v.x + v.y + v.z + v.w;
    }
    #pragma unroll
    for (int o = 32; o > 0; o >>= 1) s += __shfl_xor(s, o);
    if (lane == 0) cvec[row] = 0.01f * s + bo[row];
  }
}

// ---------------------------------------------------------------------------
// attn_out[row] = LN(hidden[row] + cvec) -> bf16.  4 rows/block (wave each).
// ---------------------------------------------------------------------------
__global__ __launch_bounds__(256)
void ln1_kernel(const float* __restrict__ hid, const float* __restrict__ cvec,
                const float* __restrict__ g, const float* __restrict__ b,
                bf16* __restrict__ out) {
  int row  = blockIdx.x * 4 + (threadIdx.x >> 6);
  int lane = threadIdx.x & 63;
  const float4* hrow = (const float4*)(hid + (size_t)row * DM);
  const float4* cv4  = (const float4*)cvec;
  float x[12];
  float s = 0.f, sq = 0.f;
  #pragma unroll
  for (int t = 0; t < 3; ++t) {
    int c = lane + t * 64;
    float4 v = hrow[c];
    float4 cc = cv4[c];
    float x0 = v.x + cc.x, x1 = v.y + cc.y, x2 = v.z + cc.z, x3 = v.w + cc.w;
    x[t*4+0] = x0; x[t*4+1] = x1; x[t*4+2] = x2; x[t*4+3] = x3;
    s  += x0 + x1 + x2 + x3;
    sq += x0*x0 + x1*x1 + x2*x2 + x3*x3;
  }
  #pragma unroll
  for (int o = 32; o > 0; o >>= 1) { s += __shfl_xor(s, o); sq += __shfl_xor(sq, o); }
  float mu  = s * (1.0f / DM);
  float var = sq * (1.0f / DM) - mu * mu;
  float inv = rsqrtf(var + 1e-12f);
  const float4* g4 = (const float4*)g;
  const float4* b4 = (const float4*)b;
  #pragma unroll
  for (int t = 0; t < 3; ++t) {
    int c = lane + t * 64;
    float4 gg = g4[c], bb = b4[c];
    bf16x4 o4;
    o4[0] = (bf16)((x[t*4+0] - mu) * inv * gg.x + bb.x);
    o4[1] = (bf16)((x[t*4+1] - mu) * inv * gg.y + bb.y);
    o4[2] = (bf16)((x[t*4+2] - mu) * inv * gg.z + bb.z);
    o4[3] = (bf16)((x[t*4+3] - mu) * inv * gg.w + bb.w);
    *(bf16x4*)(out + (size_t)row * DM + c * 4) = o4;
  }
}

// ---------------------------------------------------------------------------
// out[row] = LN( p0 + p1 + bias + attn )   (bf16 partials) -> fp32 out
// ---------------------------------------------------------------------------
__global__ __launch_bounds__(256)
void ln2_kernel(const bf16* __restrict__ p0, const bf16* __restrict__ p1,
                const float* __restrict__ bias, const bf16* __restrict__ attn,
                const float* __restrict__ g, const float* __restrict__ b,
                float* __restrict__ out) {
  int row  = blockIdx.x * 4 + (threadIdx.x >> 6);
  int lane = threadIdx.x & 63;
  const bf16* r0 = p0 + (size_t)row * DM;
  const bf16* r1 = p1 + (size_t)row * DM;
  const bf16* ar = attn + (size_t)row * DM;
  const float4* bi4 = (const float4*)bias;
  float x[12];
  float s = 0.f, sq = 0.f;
  #pragma unroll
  for (int t = 0; t < 3; ++t) {
    int c = lane + t * 64;
    bf16x4 a = *(const bf16x4*)(r0 + c * 4);
    bf16x4 d = *(const bf16x4*)(r1 + c * 4);
    bf16x4 rv = *(const bf16x4*)(ar + c * 4);
    float4 bb = bi4[c];
    float x0 = (float)a[0] + (float)d[0] + bb.x + (float)rv[0];
    float x1 = (float)a[1] + (float)d[1] + bb.y + (float)rv[1];
    float x2 = (float)a[2] + (float)d[2] + bb.z + (float)rv[2];
    float x3 = (float)a[3] + (float)d[3] + bb.w + (float)rv[3];
    x[t*4+0] = x0; x[t*4+1] = x1; x[t*4+2] = x2; x[t*4+3] = x3;
    s  += x0 + x1 + x2 + x3;
    sq += x0*x0 + x1*x1 + x2*x2 + x3*x3;
  }
  #pragma unroll
  for (int o = 32; o > 0; o >>= 1) { s += __shfl_xor(s, o); sq += __shfl_xor(sq, o); }
  float mu  = s * (1.0f / DM);
  float var = sq * (1.0f / DM) - mu * mu;
  float inv = rsqrtf(var + 1e-12f);
  const float4* g4 = (const float4*)g;
  const float4* b4 = (const float4*)b;
  float4* orow = (float4*)(out + (size_t)row * DM);
  #pragma unroll
  for (int t = 0; t < 3; ++t) {
    int c = lane + t * 64;
    float4 gg = g4[c], bb = b4[c];
    float4 o;
    o.x = (x[t*4+0] - mu) * inv * gg.x + bb.x;
    o.y = (x[t*4+1] - mu) * inv * gg.y + bb.y;
    o.z = (x[t*4+2] - mu) * inv * gg.z + bb.z;
    o.w = (x[t*4+3] - mu) * inv * gg.w + bb.w;
    orow[c] = o;
  }
}

// ---------------------------------------------------------------------------
// NT bf16 MFMA GEMM, 128x128 tile, BK=64.  4 waves, each 64x64 as 2x2 of
// v_mfma_f32_32x32x16_bf16 (half the MFMA instructions of 16x16x32 at equal
// FLOPs; ~17% less matrix-pipe time per m119).
// A-frag (32x32x16): lane l holds A[m = l&31][k = (l>>5)*8 + j], j=0..7.
// C/D  (32x32):      col = lane&31, row = (reg&3) + 8*(reg>>2) + 4*(lane>>5).
// XOR-swizzled LDS staging; coalesced LDS-transposed epilogue.
// Grid (ygroups, xz): id%8 == y%8 -> same-m blocks share an XCD.
// ---------------------------------------------------------------------------
#define BM 128
#define BN 128
#define BK 64
#define ES 136   // epilogue LDS row stride in bf16 (272 B, 16B-aligned)

template <int EPI>
__global__ __launch_bounds__(256)
void gemm_nt(const bf16* __restrict__ A, const bf16* __restrict__ B,
             const float* __restrict__ bias,
             bf16* __restrict__ out, int M, int N, int K, int ksplit, int NB) {
  __shared__ __align__(16) unsigned char smem[BM * ES * 2];  // 34816 B
  bf16* lds_a = (bf16*)smem;
  bf16* lds_b = lds_a + BM * BK;

  const int tid   = threadIdx.x;
  const int wave  = tid >> 6;
  const int lane  = tid & 63;
  const int l31   = lane & 31;
  const int lhi   = lane >> 5;          // k-half selector for 32x32 frags
  const int xorv  = lane & 7;           // reader-side swizzle key (row&7)

  const int ygrp = blockIdx.x;          // m-row-group (fast index -> XCD key)
  const int xz   = blockIdx.y;
  const int xb   = xz % NB;             // n-block
  const int zb   = xz / NB;             // k-split

  const int m0 = ygrp * BM;
  const int n0 = xb * BN;
  const int wm = (wave >> 1) * 64;
  const int wn = (wave & 1) * 64;

  const int kbeg = zb * ksplit;
  const int kend = kbeg + ksplit;

  floatx16 acc[2][2] = {};
  const bf16* Ablk = A + (size_t)m0 * K;
  const bf16* Bblk = B + (size_t)n0 * K;

  for (int kk = kbeg; kk < kend; kk += BK) {
    #pragma unroll
    for (int i = 0; i < 4; ++i) {
      int ci  = tid + 256 * i;
      int r   = ci >> 3;
      int c_g = (ci & 7) ^ (r & 7);     // swizzled source chunk
      gl2lds16(Ablk + (size_t)r * K + kk + c_g * 8, lds_a + ci * 8);
      gl2lds16(Bblk + (size_t)r * K + kk + c_g * 8, lds_b + ci * 8);
    }
    __syncthreads();

    #pragma unroll
    for (int ks = 0; ks < BK; ks += 16) {
      const int cs = ((ks >> 3) + lhi) ^ xorv;   // swizzled chunk to read
      bf16x8 af[2], bfr[2];
      #pragma unroll
      for (int i = 0; i < 2; ++i)
        af[i] = *(const bf16x8*)&lds_a[(wm + i * 32 + l31) * BK + cs * 8];
      #pragma unroll
      for (int j = 0; j < 2; ++j)
        bfr[j] = *(const bf16x8*)&lds_b[(wn + j * 32 + l31) * BK + cs * 8];
      #pragma unroll
      for (int i = 0; i < 2; ++i)
        #pragma unroll
        for (int j = 0; j < 2; ++j)
          acc[i][j] = __builtin_amdgcn_mfma_f32_32x32x16_bf16(af[i], bfr[j], acc[i][j], 0, 0, 0);
    }
    __syncthreads();
  }

  // ---- epilogue: transpose through LDS, then coalesced stores ----
  bf16* eb = (bf16*)smem;

  float bia[2];
  if constexpr (EPI == 0) {
    #pragma unroll
    for (int j = 0; j < 2; ++j) bia[j] = bias[n0 + wn + j * 32 + l31];
  }

  #pragma unroll
  for (int i = 0; i < 2; ++i) {
    #pragma unroll
    for (int j = 0; j < 2; ++j) {
      int col = wn + j * 32 + l31;
      #pragma unroll
      for (int r = 0; r < 16; ++r) {
        int row = wm + i * 32 + (r & 3) + 8 * (r >> 2) + 4 * lhi;
        float x = acc[i][j][r];
        if constexpr (EPI == 0) x = gelu_fast(x + bia[j]);
        eb[row * ES + col] = (bf16)x;
      }
    }
  }
  __syncthreads();

  bf16* outp = out + (EPI == 1 ? (size_t)zb * M * N : 0);
  const int rsub = tid >> 4;
  const int csub = (tid & 15) * 8;
  #pragma unroll
  for (int c = 0; c < 8; ++c) {
    int row = c * 16 + rsub;
    bf16x8 v = *(const bf16x8*)&eb[row * ES + csub];
    *(bf16x8*)&outp[(size_t)(m0 + row) * N + n0 + csub] = v;
  }
}

// ---------------------------------------------------------------------------
extern "C" void kernel_launch(void* const* d_in, const int* in_sizes, int n_in,
                              void* d_out, int out_size, void* d_ws, size_t ws_size,
                              hipStream_t stream) {
  (void)in_sizes; (void)n_in; (void)out_size; (void)ws_size;

  const float* hidden = (const float*)d_in[0];
  const float* Wo     = (const float*)d_in[7];
  const float* bo     = (const float*)d_in[8];
  const float* ln1_g  = (const float*)d_in[9];
  const float* ln1_b  = (const float*)d_in[10];
  const float* Wi     = (const float*)d_in[11];
  const float* bi     = (const float*)d_in[12];
  const float* Wf     = (const float*)d_in[13];
  const float* bf_    = (const float*)d_in[14];
  const float* ln2_g  = (const float*)d_in[15];
  const float* ln2_b  = (const float*)d_in[16];
  float* out = (float*)d_out;

  // workspace layout (~98 MB)
  char* w = (char*)d_ws;
  float* cvec = (float*)w;
  size_t off = 4096;
  bf16* attn = (bf16*)(w + off); off += (size_t)MROWS * DM * 2;        // 12.6 MB
  bf16* h    = (bf16*)(w + off); off += (size_t)MROWS * DF * 2;        // 50.3 MB
  bf16* pre  = (bf16*)(w + off); off += (size_t)2 * MROWS * DM * 2;    // 25.2 MB
  bf16* Wib  = (bf16*)(w + off); off += (size_t)DF * DM * 2;           // 4.7 MB
  bf16* Wfb  = (bf16*)(w + off);                                       // 4.7 MB

  // 0. weight converts + cvec, one dispatch
  prep_kernel<<<dim3(CONV_BLOCKS + CVEC_BLOCKS), dim3(256), 0, stream>>>(
      Wi, Wf, Wib, Wfb, Wo, bo, cvec);

  // 1. attn = LN1(hidden + cvec)  (bf16)
  ln1_kernel<<<dim3(MROWS / 4), dim3(256), 0, stream>>>(hidden, cvec, ln1_g, ln1_b, attn);

  // 2. h = gelu(attn @ Wi^T + bi)      M=8192 N=3072 K=768
  gemm_nt<0><<<dim3(MROWS / BM, DF / BN), dim3(256), 0, stream>>>(
      attn, Wib, bi, h, MROWS, DF, DM, DM, DF / BN);

  // 3. pre[z] = h @ Wf^T (K-half z)    M=8192 N=768 K=3072, split-K=2
  gemm_nt<1><<<dim3(MROWS / BM, (DM / BN) * 2), dim3(256), 0, stream>>>(
      h, Wfb, nullptr, pre, MROWS, DM, DF, DF / 2, DM / BN);

  // 4. out = LN2(pre0 + pre1 + bf + attn)
  ln2_kernel<<<dim3(MROWS / 4), dim3(256), 0, stream>>>(
      pre, pre + (size_t)MROWS * DM, bf_, attn, ln2_g, ln2_b, out);
}